// Round 1
// baseline (189.835 us; speedup 1.0000x reference)
//
#include <hip/hip_runtime.h>
#include <hip/hip_bf16.h>
#include <stdint.h>

#define NROWS 4096
#define DIMS  2048
#define MARGIN_F 0.3f

typedef __attribute__((ext_vector_type(8))) short bf16x8;
typedef __attribute__((ext_vector_type(4))) float f32x4;
typedef __attribute__((ext_vector_type(4))) unsigned short us4;

__device__ inline unsigned short f2bf(float x) {
  union { float f; unsigned int u; } c; c.f = x;
  unsigned int lsb = (c.u >> 16) & 1u;
  c.u += 0x7fffu + lsb;               // round-to-nearest-even
  return (unsigned short)(c.u >> 16);
}

__device__ inline void atomicMaxF(float* addr, float v) {
  if (v >= 0.f) atomicMax((int*)addr, __float_as_int(v));
  else          atomicMin((unsigned int*)addr, __float_as_uint(v));
}
__device__ inline void atomicMinF(float* addr, float v) {
  if (v >= 0.f) atomicMin((int*)addr, __float_as_int(v));
  else          atomicMax((unsigned int*)addr, __float_as_uint(v));
}

__device__ inline void load_lds16(const void* g, void* l) {
  __builtin_amdgcn_global_load_lds(
      (const __attribute__((address_space(1))) void*)(g),
      (__attribute__((address_space(3))) void*)(l), 16, 0, 0);
}

// ---------------- normalize rows to bf16 + init dap/dan ----------------
__global__ __launch_bounds__(256) void norm_kernel(const float* __restrict__ in,
                                                   short* __restrict__ l2,
                                                   float* __restrict__ dap,
                                                   float* __restrict__ dan) {
  int row = blockIdx.x;
  int t = threadIdx.x;
  const float4* rin = (const float4*)(in + (size_t)row * DIMS);
  float4 v0 = rin[t];        // elems 4t .. 4t+3
  float4 v1 = rin[t + 256];  // elems 1024+4t ..
  float ss = v0.x*v0.x + v0.y*v0.y + v0.z*v0.z + v0.w*v0.w
           + v1.x*v1.x + v1.y*v1.y + v1.z*v1.z + v1.w*v1.w;
  #pragma unroll
  for (int s = 1; s < 64; s <<= 1) ss += __shfl_xor(ss, s);
  __shared__ float wsum[4];
  if ((t & 63) == 0) wsum[t >> 6] = ss;
  __syncthreads();
  float tot = wsum[0] + wsum[1] + wsum[2] + wsum[3];
  float rn = 1.0f / sqrtf(tot);
  short* orow = l2 + (size_t)row * DIMS;
  us4 o0, o1;
  o0.x = f2bf(v0.x * rn); o0.y = f2bf(v0.y * rn);
  o0.z = f2bf(v0.z * rn); o0.w = f2bf(v0.w * rn);
  o1.x = f2bf(v1.x * rn); o1.y = f2bf(v1.y * rn);
  o1.z = f2bf(v1.z * rn); o1.w = f2bf(v1.w * rn);
  *(us4*)(orow + 4 * t) = o0;
  *(us4*)(orow + 4 * t + 1024) = o1;
  if (t == 0) { dap[row] = -__builtin_inff(); dan[row] = __builtin_inff(); }
}

// ---------------- fused GEMM (G = L . L^T) + masked row max/min ----------------
// 128x128 tile, 4 waves (2x2 of 64x64), BK=32, 16x16x32 bf16 MFMA.
// LDS chunk-major layout: chunk c = kgrp*128 + row holds L[row][k0 + kgrp*8 .. +8].
__global__ __launch_bounds__(256) void gemm_reduce_kernel(
    const short* __restrict__ l2, const int* __restrict__ tgt,
    float* __restrict__ dap, float* __restrict__ dan) {
  __shared__ __attribute__((aligned(16))) short ldsA[4096];  // 4*128*8 bf16 = 8 KB
  __shared__ __attribute__((aligned(16))) short ldsB[4096];

  int bid = blockIdx.x;
  int bi = bid >> 5, bj = bid & 31;
  int t = threadIdx.x;
  int lane = t & 63, w = t >> 6;
  int wr = w >> 1, wc = w & 1;

  f32x4 acc[4][4];
  #pragma unroll
  for (int m = 0; m < 4; m++)
    #pragma unroll
    for (int n = 0; n < 4; n++) acc[m][n] = (f32x4){0.f, 0.f, 0.f, 0.f};

  // staging: 512 16B-chunks per tile, 256 lanes -> 2 issues per tile
  int c0 = w * 64 + lane;
  int c1 = c0 + 256;
  const short* gA0 = l2 + ((size_t)(bi * 128 + (c0 & 127))) * DIMS + (c0 >> 7) * 8;
  const short* gA1 = l2 + ((size_t)(bi * 128 + (c1 & 127))) * DIMS + (c1 >> 7) * 8;
  const short* gB0 = l2 + ((size_t)(bj * 128 + (c0 & 127))) * DIMS + (c0 >> 7) * 8;
  const short* gB1 = l2 + ((size_t)(bj * 128 + (c1 & 127))) * DIMS + (c1 >> 7) * 8;
  short* lA0 = ldsA + (size_t)(w * 64) * 8;       // wave-uniform base; lane*16B auto
  short* lA1 = ldsA + (size_t)(256 + w * 64) * 8;
  short* lB0 = ldsB + (size_t)(w * 64) * 8;
  short* lB1 = ldsB + (size_t)(256 + w * 64) * 8;

  int kgrp = lane >> 4;
  int rowAf = wr * 64 + (lane & 15);
  int rowBf = wc * 64 + (lane & 15);

  for (int k0 = 0; k0 < DIMS; k0 += 32) {
    __syncthreads();               // previous tile's LDS reads done
    load_lds16(gA0 + k0, lA0);
    load_lds16(gA1 + k0, lA1);
    load_lds16(gB0 + k0, lB0);
    load_lds16(gB1 + k0, lB1);
    __syncthreads();               // staging complete (vmcnt drained by barrier)

    bf16x8 a[4], b[4];
    #pragma unroll
    for (int m = 0; m < 4; m++)
      a[m] = *(const bf16x8*)(ldsA + ((kgrp * 128) + rowAf + m * 16) * 8);
    #pragma unroll
    for (int n = 0; n < 4; n++)
      b[n] = *(const bf16x8*)(ldsB + ((kgrp * 128) + rowBf + n * 16) * 8);
    #pragma unroll
    for (int m = 0; m < 4; m++)
      #pragma unroll
      for (int n = 0; n < 4; n++)
        acc[m][n] = __builtin_amdgcn_mfma_f32_16x16x32_bf16(a[m], b[n], acc[m][n], 0, 0, 0);
  }

  // ---- fused masked reduction over this tile ----
  // acc[m][n][r] = C[wr*64 + m*16 + (lane>>4)*4 + r][wc*64 + n*16 + (lane&15)]
  int tcol[4];
  #pragma unroll
  for (int n = 0; n < 4; n++) tcol[n] = tgt[bj * 128 + wc * 64 + n * 16 + (lane & 15)];
  int rbase = bi * 128 + wr * 64 + (lane >> 4) * 4;

  #pragma unroll
  for (int m = 0; m < 4; m++) {
    #pragma unroll
    for (int r = 0; r < 4; r++) {
      int grow = rbase + m * 16 + r;
      int trow = tgt[grow];
      float ap = -__builtin_inff(), an = __builtin_inff();
      #pragma unroll
      for (int n = 0; n < 4; n++) {
        float d = -acc[m][n][r];
        if (trow == tcol[n]) ap = fmaxf(ap, d);
        else                 an = fminf(an, d);
      }
      // combine across the 16 lanes holding the same rows (different cols)
      #pragma unroll
      for (int s = 1; s < 16; s <<= 1) {
        ap = fmaxf(ap, __shfl_xor(ap, s));
        an = fminf(an, __shfl_xor(an, s));
      }
      if ((lane & 15) == 0) {
        atomicMaxF(&dap[grow], ap);
        atomicMinF(&dan[grow], an);
      }
    }
  }
}

// ---------------- final loss ----------------
__global__ __launch_bounds__(256) void loss_kernel(const float* __restrict__ dap,
                                                   const float* __restrict__ dan,
                                                   float* __restrict__ out) {
  int t = threadIdx.x;
  float s = 0.f;
  for (int i = t; i < NROWS; i += 256) {
    float v = dap[i] - dan[i] + MARGIN_F;
    s += v > 0.f ? v : 0.f;
  }
  #pragma unroll
  for (int sh = 1; sh < 64; sh <<= 1) s += __shfl_xor(s, sh);
  __shared__ float ws[4];
  if ((t & 63) == 0) ws[t >> 6] = s;
  __syncthreads();
  if (t == 0) out[0] = (ws[0] + ws[1] + ws[2] + ws[3]) * (1.0f / (float)NROWS);
}

extern "C" void kernel_launch(void* const* d_in, const int* in_sizes, int n_in,
                              void* d_out, int out_size, void* d_ws, size_t ws_size,
                              hipStream_t stream) {
  const float* inputs = (const float*)d_in[0];
  const int* targets = (const int*)d_in[1];
  short* l2 = (short*)d_ws;
  float* dap = (float*)((char*)d_ws + (size_t)NROWS * DIMS * 2);
  float* dan = dap + NROWS;
  float* out = (float*)d_out;

  hipLaunchKernelGGL(norm_kernel, dim3(NROWS), dim3(256), 0, stream,
                     inputs, l2, dap, dan);
  hipLaunchKernelGGL(gemm_reduce_kernel, dim3(1024), dim3(256), 0, stream,
                     l2, targets, dap, dan);
  hipLaunchKernelGGL(loss_kernel, dim3(1), dim3(256), 0, stream, dap, dan, out);
}

// Round 2
// 166.754 us; speedup vs baseline: 1.1384x; 1.1384x over previous
//
#include <hip/hip_runtime.h>
#include <hip/hip_bf16.h>
#include <stdint.h>

#define NROWS 4096
#define DIMS  2048
#define NT    32          // 4096/128 tiles per dim
#define NBLK  (NT*(NT+1)/2)   // 528 upper-tri tiles
#define MARGIN_F 0.3f

typedef __attribute__((ext_vector_type(8))) short bf16x8;
typedef __attribute__((ext_vector_type(4))) float f32x4;
typedef __attribute__((ext_vector_type(4))) unsigned short us4;

__device__ inline unsigned short f2bf(float x) {
  union { float f; unsigned int u; } c; c.f = x;
  unsigned int lsb = (c.u >> 16) & 1u;
  c.u += 0x7fffu + lsb;               // round-to-nearest-even
  return (unsigned short)(c.u >> 16);
}

__device__ inline void atomicMaxF(float* addr, float v) {
  if (v >= 0.f) atomicMax((int*)addr, __float_as_int(v));
  else          atomicMin((unsigned int*)addr, __float_as_uint(v));
}
__device__ inline void atomicMinF(float* addr, float v) {
  if (v >= 0.f) atomicMin((int*)addr, __float_as_int(v));
  else          atomicMax((unsigned int*)addr, __float_as_uint(v));
}

__device__ inline void load_lds16(const void* g, void* l) {
  __builtin_amdgcn_global_load_lds(
      (const __attribute__((address_space(1))) void*)(g),
      (__attribute__((address_space(3))) void*)(l), 16, 0, 0);
}

// ---------------- normalize rows to bf16 + init dap/dan ----------------
__global__ __launch_bounds__(256) void norm_kernel(const float* __restrict__ in,
                                                   short* __restrict__ l2,
                                                   float* __restrict__ dap,
                                                   float* __restrict__ dan) {
  int row = blockIdx.x;
  int t = threadIdx.x;
  const float4* rin = (const float4*)(in + (size_t)row * DIMS);
  float4 v0 = rin[t];
  float4 v1 = rin[t + 256];
  float ss = v0.x*v0.x + v0.y*v0.y + v0.z*v0.z + v0.w*v0.w
           + v1.x*v1.x + v1.y*v1.y + v1.z*v1.z + v1.w*v1.w;
  #pragma unroll
  for (int s = 1; s < 64; s <<= 1) ss += __shfl_xor(ss, s);
  __shared__ float wsum[4];
  if ((t & 63) == 0) wsum[t >> 6] = ss;
  __syncthreads();
  float tot = wsum[0] + wsum[1] + wsum[2] + wsum[3];
  float rn = 1.0f / sqrtf(tot);
  short* orow = l2 + (size_t)row * DIMS;
  us4 o0, o1;
  o0.x = f2bf(v0.x * rn); o0.y = f2bf(v0.y * rn);
  o0.z = f2bf(v0.z * rn); o0.w = f2bf(v0.w * rn);
  o1.x = f2bf(v1.x * rn); o1.y = f2bf(v1.y * rn);
  o1.z = f2bf(v1.z * rn); o1.w = f2bf(v1.w * rn);
  *(us4*)(orow + 4 * t) = o0;
  *(us4*)(orow + 4 * t + 1024) = o1;
  if (t == 0) { dap[row] = -__builtin_inff(); dan[row] = __builtin_inff(); }
}

// ---------------- fused symmetric GEMM + masked row/col max/min ----------------
// Upper-triangular 128x128 tiles only (bi<=bj). 4 waves (2x2 of 64x64), BK=32,
// 16x16x32 bf16 MFMA, double-buffered LDS (stage next tile before computing current).
__global__ __launch_bounds__(256) void gemm_reduce_kernel(
    const short* __restrict__ l2, const int* __restrict__ tgt,
    float* __restrict__ dap, float* __restrict__ dan) {
  __shared__ __attribute__((aligned(16))) short ldsA[2][4096];  // 2 x 8 KB
  __shared__ __attribute__((aligned(16))) short ldsB[2][4096];

  // map linear bid -> upper-tri (bi, bj), bi <= bj
  int bid = blockIdx.x;
  int bi = 0, rem = bid;
  #pragma unroll 1
  while (rem >= NT - bi) { rem -= NT - bi; ++bi; }
  int bj = bi + rem;

  int t = threadIdx.x;
  int lane = t & 63, w = t >> 6;
  int wr = w >> 1, wc = w & 1;

  f32x4 acc[4][4];
  #pragma unroll
  for (int m = 0; m < 4; m++)
    #pragma unroll
    for (int n = 0; n < 4; n++) acc[m][n] = (f32x4){0.f, 0.f, 0.f, 0.f};

  // staging: 512 16B-chunks per operand tile, 256 threads -> 2 issues each
  int c0 = w * 64 + lane;
  int c1 = c0 + 256;
  const short* gA0 = l2 + ((size_t)(bi * 128 + (c0 & 127))) * DIMS + (c0 >> 7) * 8;
  const short* gA1 = l2 + ((size_t)(bi * 128 + (c1 & 127))) * DIMS + (c1 >> 7) * 8;
  const short* gB0 = l2 + ((size_t)(bj * 128 + (c0 & 127))) * DIMS + (c0 >> 7) * 8;
  const short* gB1 = l2 + ((size_t)(bj * 128 + (c1 & 127))) * DIMS + (c1 >> 7) * 8;
  int s0 = (w * 64) * 8;          // wave-uniform LDS base (shorts); lane*16B implicit
  int s1 = (256 + w * 64) * 8;

  int kgrp = lane >> 4;
  int rowAf = wr * 64 + (lane & 15);
  int rowBf = wc * 64 + (lane & 15);

  // prologue: stage tile 0 into buffer 0
  load_lds16(gA0, &ldsA[0][s0]);
  load_lds16(gA1, &ldsA[0][s1]);
  load_lds16(gB0, &ldsB[0][s0]);
  load_lds16(gB1, &ldsB[0][s1]);
  __syncthreads();

  int cur = 0;
  for (int k0 = 32; k0 < DIMS; k0 += 32) {
    // issue next-tile loads first (in flight across the whole compute phase)
    load_lds16(gA0 + k0, &ldsA[cur ^ 1][s0]);
    load_lds16(gA1 + k0, &ldsA[cur ^ 1][s1]);
    load_lds16(gB0 + k0, &ldsB[cur ^ 1][s0]);
    load_lds16(gB1 + k0, &ldsB[cur ^ 1][s1]);

    bf16x8 a[4], b[4];
    #pragma unroll
    for (int m = 0; m < 4; m++)
      a[m] = *(const bf16x8*)(&ldsA[cur][((kgrp * 128) + rowAf + m * 16) * 8]);
    #pragma unroll
    for (int n = 0; n < 4; n++)
      b[n] = *(const bf16x8*)(&ldsB[cur][((kgrp * 128) + rowBf + n * 16) * 8]);
    #pragma unroll
    for (int m = 0; m < 4; m++)
      #pragma unroll
      for (int n = 0; n < 4; n++)
        acc[m][n] = __builtin_amdgcn_mfma_f32_16x16x32_bf16(a[m], b[n], acc[m][n], 0, 0, 0);

    __syncthreads();   // drains vmcnt (next buffer staged) + all reads of cur done
    cur ^= 1;
  }
  // epilogue tile (no prefetch)
  {
    bf16x8 a[4], b[4];
    #pragma unroll
    for (int m = 0; m < 4; m++)
      a[m] = *(const bf16x8*)(&ldsA[cur][((kgrp * 128) + rowAf + m * 16) * 8]);
    #pragma unroll
    for (int n = 0; n < 4; n++)
      b[n] = *(const bf16x8*)(&ldsB[cur][((kgrp * 128) + rowBf + n * 16) * 8]);
    #pragma unroll
    for (int m = 0; m < 4; m++)
      #pragma unroll
      for (int n = 0; n < 4; n++)
        acc[m][n] = __builtin_amdgcn_mfma_f32_16x16x32_bf16(a[m], b[n], acc[m][n], 0, 0, 0);
  }

  // ---- fused masked reduction ----
  // acc[m][n][r] = G[bi*128 + wr*64 + m*16 + (lane>>4)*4 + r][bj*128 + wc*64 + n*16 + (lane&15)]
  int tcol[4];
  #pragma unroll
  for (int n = 0; n < 4; n++) tcol[n] = tgt[bj * 128 + wc * 64 + n * 16 + (lane & 15)];
  int rbase = bi * 128 + wr * 64 + (lane >> 4) * 4;

  float apc[4], anc[4];   // per-column partials (for the transposed contribution)
  #pragma unroll
  for (int n = 0; n < 4; n++) { apc[n] = -__builtin_inff(); anc[n] = __builtin_inff(); }

  #pragma unroll
  for (int m = 0; m < 4; m++) {
    #pragma unroll
    for (int r = 0; r < 4; r++) {
      int grow = rbase + m * 16 + r;
      int trow = tgt[grow];
      float ap = -__builtin_inff(), an = __builtin_inff();
      #pragma unroll
      for (int n = 0; n < 4; n++) {
        float d = -acc[m][n][r];
        bool same = (trow == tcol[n]);
        ap = same ? fmaxf(ap, d) : ap;
        an = same ? an : fminf(an, d);
        apc[n] = same ? fmaxf(apc[n], d) : apc[n];
        anc[n] = same ? anc[n] : fminf(anc[n], d);
      }
      // reduce across the 16 lanes holding this row (different cols)
      #pragma unroll
      for (int s = 1; s < 16; s <<= 1) {
        ap = fmaxf(ap, __shfl_xor(ap, s));
        an = fminf(an, __shfl_xor(an, s));
      }
      if ((lane & 15) == 0) {
        atomicMaxF(&dap[grow], ap);
        atomicMinF(&dan[grow], an);
      }
    }
  }

  if (bi != bj) {
    // transposed contribution: per-column max/min over this tile's rows -> rows bj*128..
    #pragma unroll
    for (int n = 0; n < 4; n++) {
      float ap = apc[n], an = anc[n];
      // combine across lanes sharing the same column (lane>>4 differs)
      ap = fmaxf(ap, __shfl_xor(ap, 16));
      ap = fmaxf(ap, __shfl_xor(ap, 32));
      an = fminf(an, __shfl_xor(an, 16));
      an = fminf(an, __shfl_xor(an, 32));
      if ((lane >> 4) == 0) {
        int gcol = bj * 128 + wc * 64 + n * 16 + lane;  // lane = lane&15 here
        atomicMaxF(&dap[gcol], ap);
        atomicMinF(&dan[gcol], an);
      }
    }
  }
}

// ---------------- final loss ----------------
__global__ __launch_bounds__(256) void loss_kernel(const float* __restrict__ dap,
                                                   const float* __restrict__ dan,
                                                   float* __restrict__ out) {
  int t = threadIdx.x;
  float s = 0.f;
  for (int i = t; i < NROWS; i += 256) {
    float v = dap[i] - dan[i] + MARGIN_F;
    s += v > 0.f ? v : 0.f;
  }
  #pragma unroll
  for (int sh = 1; sh < 64; sh <<= 1) s += __shfl_xor(s, sh);
  __shared__ float ws[4];
  if ((t & 63) == 0) ws[t >> 6] = s;
  __syncthreads();
  if (t == 0) out[0] = (ws[0] + ws[1] + ws[2] + ws[3]) * (1.0f / (float)NROWS);
}

extern "C" void kernel_launch(void* const* d_in, const int* in_sizes, int n_in,
                              void* d_out, int out_size, void* d_ws, size_t ws_size,
                              hipStream_t stream) {
  const float* inputs = (const float*)d_in[0];
  const int* targets = (const int*)d_in[1];
  short* l2 = (short*)d_ws;
  float* dap = (float*)((char*)d_ws + (size_t)NROWS * DIMS * 2);
  float* dan = dap + NROWS;
  float* out = (float*)d_out;

  hipLaunchKernelGGL(norm_kernel, dim3(NROWS), dim3(256), 0, stream,
                     inputs, l2, dap, dan);
  hipLaunchKernelGGL(gemm_reduce_kernel, dim3(NBLK), dim3(256), 0, stream,
                     l2, targets, dap, dan);
  hipLaunchKernelGGL(loss_kernel, dim3(1), dim3(256), 0, stream, dap, dan, out);
}